// Round 1
// baseline (484.564 us; speedup 1.0000x reference)
//
#include <hip/hip_runtime.h>
#include <stdint.h>

// ---------- helpers ----------
__device__ __forceinline__ float bf16_to_f(uint16_t u) {
    union { uint32_t i; float f; } v; v.i = ((uint32_t)u) << 16; return v.f;
}
__device__ __forceinline__ uint16_t f_to_bf16(float f) {
    union { uint32_t i; float f; } v; v.f = f;
    uint32_t u = v.i;
    u += 0x7FFFu + ((u >> 16) & 1u);   // round-to-nearest-even
    return (uint16_t)(u >> 16);
}

#define B_  32
#define T_  512
#define CF_ 2048
#define H_  128
#define G4_ 512   // 4*H

// =====================================================================
// K1: Hfc[b][d][t] = b_fc1[d] + sum_cf W_fc1[d][cf] * x[b][cf][t]
//     per-b GEMM (128x2048)@(2048x512), 64x64 tile, 4x4/thread
// =====================================================================
__global__ __launch_bounds__(256) void k_fc1(const float* __restrict__ x,
                                             const float* __restrict__ Wfc,
                                             const float* __restrict__ bfc,
                                             float* __restrict__ Hfc) {
    __shared__ float As[16][68];   // [k][m], padded
    __shared__ float Bs[16][64];   // [k][n]
    const int b  = blockIdx.z;
    const int m0 = blockIdx.y * 64;
    const int n0 = blockIdx.x * 64;
    const int tid = threadIdx.x;
    const int tx = tid & 15, ty = tid >> 4;

    const float* Ap = Wfc + (size_t)(m0 + (tid >> 2)) * CF_ + (tid & 3) * 4;
    const float* Bp = x + (size_t)b * CF_ * T_ + (size_t)(tid >> 4) * T_ + n0 + (tid & 15) * 4;

    float acc[4][4] = {};
    for (int k0 = 0; k0 < CF_; k0 += 16) {
        float4 av = *(const float4*)(Ap + k0);
        float4 bv = *(const float4*)(Bp + (size_t)k0 * T_);
        __syncthreads();
        {
            int m = tid >> 2, kq = (tid & 3) * 4;
            As[kq + 0][m] = av.x; As[kq + 1][m] = av.y;
            As[kq + 2][m] = av.z; As[kq + 3][m] = av.w;
            *(float4*)&Bs[tid >> 4][(tid & 15) * 4] = bv;
        }
        __syncthreads();
        #pragma unroll
        for (int kk = 0; kk < 16; ++kk) {
            float4 a = *(float4*)&As[kk][ty * 4];
            float4 q = *(float4*)&Bs[kk][tx * 4];
            float ar[4] = {a.x, a.y, a.z, a.w};
            float br[4] = {q.x, q.y, q.z, q.w};
            #pragma unroll
            for (int i = 0; i < 4; ++i)
                #pragma unroll
                for (int j = 0; j < 4; ++j) acc[i][j] += ar[i] * br[j];
        }
    }
    #pragma unroll
    for (int i = 0; i < 4; ++i) {
        int d = m0 + ty * 4 + i;
        float bias = bfc[d];
        float4 o = {acc[i][0] + bias, acc[i][1] + bias, acc[i][2] + bias, acc[i][3] + bias};
        *(float4*)&Hfc[((size_t)b * H_ + d) * T_ + n0 + tx * 4] = o;
    }
}

// =====================================================================
// K2: Xp[dir][b][t][g] = bf16( bias_dir[g] + sum_d Hfc[b][d][t]*Wih_dir[g][d] )
//     GEMM (t x d)@(d x g): A' = Hfc[b]^T, B' = Wih^T. 64x64 tile.
// =====================================================================
__global__ __launch_bounds__(256) void k_xproj(const float* __restrict__ Hfc,
                                               const float* __restrict__ Wih_f,
                                               const float* __restrict__ Wih_b,
                                               const float* __restrict__ b_f,
                                               const float* __restrict__ b_b,
                                               uint16_t* __restrict__ Xp) {
    __shared__ float As[16][64];   // [k][t]
    __shared__ float Bs[16][68];   // [k][g], padded (scatter writes)
    const int db  = blockIdx.z;        // dir*32 + b
    const int dir = db >> 5;
    const int b   = db & 31;
    const int t0  = blockIdx.y * 64;
    const int g0  = blockIdx.x * 64;
    const int tid = threadIdx.x;
    const int tx = tid & 15, ty = tid >> 4;
    const float* W  = dir ? Wih_b : Wih_f;
    const float* bi = dir ? b_b   : b_f;

    float acc[4][4] = {};
    for (int k0 = 0; k0 < H_; k0 += 16) {
        // A: Hfc[b][k0+kk][t0 + tq*4 ..]  (coalesced, direct store)
        float4 av = *(const float4*)&Hfc[((size_t)b * H_ + k0 + (tid >> 4)) * T_ + t0 + (tid & 15) * 4];
        // B: Wih[g0+gn][k0 + kq*4 ..]  -> transpose into Bs
        float4 wv = *(const float4*)&W[(size_t)(g0 + (tid >> 2)) * H_ + k0 + (tid & 3) * 4];
        __syncthreads();
        {
            *(float4*)&As[tid >> 4][(tid & 15) * 4] = av;
            int gn = tid >> 2, kq = (tid & 3) * 4;
            Bs[kq + 0][gn] = wv.x; Bs[kq + 1][gn] = wv.y;
            Bs[kq + 2][gn] = wv.z; Bs[kq + 3][gn] = wv.w;
        }
        __syncthreads();
        #pragma unroll
        for (int kk = 0; kk < 16; ++kk) {
            float4 a = *(float4*)&As[kk][ty * 4];
            float4 q = *(float4*)&Bs[kk][tx * 4];
            float ar[4] = {a.x, a.y, a.z, a.w};
            float br[4] = {q.x, q.y, q.z, q.w};
            #pragma unroll
            for (int i = 0; i < 4; ++i)
                #pragma unroll
                for (int j = 0; j < 4; ++j) acc[i][j] += ar[i] * br[j];
        }
    }
    float bj[4];
    #pragma unroll
    for (int j = 0; j < 4; ++j) bj[j] = bi[g0 + tx * 4 + j];
    #pragma unroll
    for (int i = 0; i < 4; ++i) {
        int t = t0 + ty * 4 + i;
        ushort4 st;
        st.x = f_to_bf16(acc[i][0] + bj[0]);
        st.y = f_to_bf16(acc[i][1] + bj[1]);
        st.z = f_to_bf16(acc[i][2] + bj[2]);
        st.w = f_to_bf16(acc[i][3] + bj[3]);
        *(ushort4*)&Xp[((size_t)db * T_ + t) * G4_ + g0 + tx * 4] = st;
    }
}

// =====================================================================
// K3: LSTM recurrence. 512 independent sequences per direction (t-frames).
//     One WG = 512 threads (one gate each) handles 4 t-values, one dir.
//     Whh row cached in 32xfloat4 VGPRs; h broadcast from LDS.
// =====================================================================
__global__ __launch_bounds__(512) void k_lstm(const uint16_t* __restrict__ Xp,
                                              const float* __restrict__ Whh_f,
                                              const float* __restrict__ Whh_b,
                                              float* __restrict__ hs) {
    __shared__ float h_sh[4][H_];
    __shared__ float z_sh[4][G4_];
    const int dir = blockIdx.y;
    const int t0  = blockIdx.x * 4;
    const int g   = threadIdx.x;
    const float* Whh = dir ? Whh_b : Whh_f;

    float4 wr[32];
    #pragma unroll
    for (int i = 0; i < 32; ++i) wr[i] = *(const float4*)&Whh[(size_t)g * H_ + i * 4];

    const int hh  = threadIdx.x & (H_ - 1);
    const int tt2 = threadIdx.x >> 7;
    h_sh[tt2][hh] = 0.f;
    float c_reg = 0.f;
    __syncthreads();

    for (int s = 0; s < 32; ++s) {
        const int b_idx = dir ? (31 - s) : s;
        const uint16_t* xp = Xp + ((size_t)(dir * B_ + b_idx) * T_ + t0) * G4_ + g;
        float acc0 = bf16_to_f(xp[0]);
        float acc1 = bf16_to_f(xp[G4_]);
        float acc2 = bf16_to_f(xp[2 * G4_]);
        float acc3 = bf16_to_f(xp[3 * G4_]);
        #pragma unroll
        for (int d4 = 0; d4 < 32; ++d4) {
            float4 w  = wr[d4];
            float4 h0 = *(float4*)&h_sh[0][d4 * 4];
            float4 h1 = *(float4*)&h_sh[1][d4 * 4];
            float4 h2 = *(float4*)&h_sh[2][d4 * 4];
            float4 h3 = *(float4*)&h_sh[3][d4 * 4];
            acc0 += w.x * h0.x; acc0 += w.y * h0.y; acc0 += w.z * h0.z; acc0 += w.w * h0.w;
            acc1 += w.x * h1.x; acc1 += w.y * h1.y; acc1 += w.z * h1.z; acc1 += w.w * h1.w;
            acc2 += w.x * h2.x; acc2 += w.y * h2.y; acc2 += w.z * h2.z; acc2 += w.w * h2.w;
            acc3 += w.x * h3.x; acc3 += w.y * h3.y; acc3 += w.z * h3.z; acc3 += w.w * h3.w;
        }
        z_sh[0][g] = acc0; z_sh[1][g] = acc1; z_sh[2][g] = acc2; z_sh[3][g] = acc3;
        __syncthreads();
        // gate combine: thread -> (tt2, hh)
        float zi = z_sh[tt2][hh];
        float zf = z_sh[tt2][hh + 128];
        float zg = z_sh[tt2][hh + 256];
        float zo = z_sh[tt2][hh + 384];
        float si = 1.f / (1.f + __expf(-zi));
        float sf = 1.f / (1.f + __expf(-zf));
        float so = 1.f / (1.f + __expf(-zo));
        float eg = __expf(2.f * zg);
        float tg = 1.f - 2.f / (eg + 1.f);
        c_reg = sf * c_reg + si * tg;
        float ec = __expf(2.f * c_reg);
        float tc = 1.f - 2.f / (ec + 1.f);
        float hn = so * tc;
        h_sh[tt2][hh] = hn;
        hs[((size_t)b_idx * T_ + t0 + tt2) * 256 + dir * H_ + hh] = hn;
        __syncthreads();
    }
}

// =====================================================================
// K4: out[b][e][t] = b_out[e] + sum_{k<256} W_out[e][k] * hs[b][t][k]
// =====================================================================
__global__ __launch_bounds__(256) void k_out(const float* __restrict__ hs,
                                             const float* __restrict__ Wout,
                                             const float* __restrict__ bout,
                                             float* __restrict__ out) {
    __shared__ float As[16][68];   // [k][e]
    __shared__ float Bs[16][68];   // [k][t]
    const int b  = blockIdx.z;
    const int m0 = blockIdx.y * 64;
    const int n0 = blockIdx.x * 64;
    const int tid = threadIdx.x;
    const int tx = tid & 15, ty = tid >> 4;

    float acc[4][4] = {};
    for (int k0 = 0; k0 < 256; k0 += 16) {
        float4 av = *(const float4*)&Wout[(size_t)(m0 + (tid >> 2)) * 256 + k0 + (tid & 3) * 4];
        float4 bv = *(const float4*)&hs[((size_t)b * T_ + n0 + (tid >> 2)) * 256 + k0 + (tid & 3) * 4];
        __syncthreads();
        {
            int r = tid >> 2, kq = (tid & 3) * 4;
            As[kq + 0][r] = av.x; As[kq + 1][r] = av.y;
            As[kq + 2][r] = av.z; As[kq + 3][r] = av.w;
            Bs[kq + 0][r] = bv.x; Bs[kq + 1][r] = bv.y;
            Bs[kq + 2][r] = bv.z; Bs[kq + 3][r] = bv.w;
        }
        __syncthreads();
        #pragma unroll
        for (int kk = 0; kk < 16; ++kk) {
            float4 a = *(float4*)&As[kk][ty * 4];
            float4 q = *(float4*)&Bs[kk][tx * 4];
            float ar[4] = {a.x, a.y, a.z, a.w};
            float br[4] = {q.x, q.y, q.z, q.w};
            #pragma unroll
            for (int i = 0; i < 4; ++i)
                #pragma unroll
                for (int j = 0; j < 4; ++j) acc[i][j] += ar[i] * br[j];
        }
    }
    #pragma unroll
    for (int i = 0; i < 4; ++i) {
        int e = m0 + ty * 4 + i;
        float bias = bout[e];
        float4 o = {acc[i][0] + bias, acc[i][1] + bias, acc[i][2] + bias, acc[i][3] + bias};
        *(float4*)&out[((size_t)b * H_ + e) * T_ + n0 + tx * 4] = o;
    }
}

// =====================================================================
extern "C" void kernel_launch(void* const* d_in, const int* in_sizes, int n_in,
                              void* d_out, int out_size, void* d_ws, size_t ws_size,
                              hipStream_t stream) {
    const float* x     = (const float*)d_in[0];
    const float* Wfc   = (const float*)d_in[1];
    const float* bfc   = (const float*)d_in[2];
    const float* Wih_f = (const float*)d_in[3];
    const float* Whh_f = (const float*)d_in[4];
    const float* b_f   = (const float*)d_in[5];
    const float* Wih_b = (const float*)d_in[6];
    const float* Whh_b = (const float*)d_in[7];
    const float* b_b   = (const float*)d_in[8];
    const float* Wout  = (const float*)d_in[9];
    const float* bout  = (const float*)d_in[10];
    float* out = (float*)d_out;

    char* ws = (char*)d_ws;
    float*    Hfc = (float*)ws;                               // 32*128*512*4  =  8 MB
    uint16_t* Xp  = (uint16_t*)(ws + (size_t)(8 << 20));      // 2*32*512*512*2 = 32 MB
    float*    hs  = (float*)(ws + (size_t)(40 << 20));        // 32*512*256*4  = 16 MB
                                                              // total 56 MB

    k_fc1  <<<dim3(8, 2, 32), 256, 0, stream>>>(x, Wfc, bfc, Hfc);
    k_xproj<<<dim3(8, 8, 64), 256, 0, stream>>>(Hfc, Wih_f, Wih_b, b_f, b_b, Xp);
    k_lstm <<<dim3(128, 2),   512, 0, stream>>>(Xp, Whh_f, Whh_b, hs);
    k_out  <<<dim3(8, 2, 32), 256, 0, stream>>>(hs, Wout, bout, out);
}

// Round 2
// 399.750 us; speedup vs baseline: 1.2122x; 1.2122x over previous
//
#include <hip/hip_runtime.h>
#include <stdint.h>

typedef __attribute__((ext_vector_type(8))) short short8;
typedef __attribute__((ext_vector_type(4))) float floatx4;

// ---------- helpers ----------
__device__ __forceinline__ float bf16_to_f(uint16_t u) {
    union { uint32_t i; float f; } v; v.i = ((uint32_t)u) << 16; return v.f;
}
__device__ __forceinline__ uint16_t f_to_bf16(float f) {
    union { uint32_t i; float f; } v; v.f = f;
    uint32_t u = v.i;
    u += 0x7FFFu + ((u >> 16) & 1u);   // round-to-nearest-even
    return (uint16_t)(u >> 16);
}
__device__ __forceinline__ void gload16(const void* g, void* l) {
    __builtin_amdgcn_global_load_lds(
        (const __attribute__((address_space(1))) void*)g,
        (__attribute__((address_space(3))) void*)l, 16, 0, 0);
}

#define B_  32
#define T_  512
#define CF_ 2048
#define H_  128
#define G4_ 512   // 4*H

// =====================================================================
// Generic MFMA tile core: C(128 x 64) += A(128 x K) * B(64 x K)^T
// A,B bf16 with K contiguous rows. BK=32. 256 threads = 4 waves,
// wave w covers (wm=64*(w>>1), wn=32*(w&1)), 4x2 frags of 16x16.
// LDS layout is k-chunk-major: chunk(kc,row) at 16B offset (kc*R + row)
// so frag ds_read_b128 is bank-conflict-free and global_load_lds's
// "base + lane*16" constraint is satisfied.
// =====================================================================
__device__ __forceinline__ void gemm_core(const uint16_t* __restrict__ A,
                                          const uint16_t* __restrict__ B,
                                          int K, uint16_t* As, uint16_t* Bs,
                                          floatx4 acc[4][2]) {
    const int tid = threadIdx.x;
    const int w = tid >> 6, l = tid & 63;
    const int wm = (w >> 1) * 64, wn = (w & 1) * 32;
    // staging source rows (per lane) and k-chunk (per wave)
    const uint16_t* gA0 = A + (size_t)l * K;          // rows 0..63   (j=0)
    const uint16_t* gA1 = A + (size_t)(64 + l) * K;   // rows 64..127 (j=1)
    const uint16_t* gB  = B + (size_t)l * K;
    const int kcs = w * 8;                            // wave w stages k-chunk w
    uint16_t* ldsA = As + w * 1024;                   // chunk (w*128)*8 shorts
    uint16_t* ldsB = Bs + w * 512;                    // chunk (w*64)*8 shorts
    const int lm = l & 15, lk = l >> 4;

    for (int k0 = 0; k0 < K; k0 += 32) {
        __syncthreads();
        gload16(gA0 + k0 + kcs, ldsA);
        gload16(gA1 + k0 + kcs, ldsA + 512);
        gload16(gB  + k0 + kcs, ldsB);
        __syncthreads();
        short8 a[4], b[2];
        #pragma unroll
        for (int mf = 0; mf < 4; ++mf)
            a[mf] = *(const short8*)&As[(size_t)(lk * 128 + wm + mf * 16 + lm) * 8];
        #pragma unroll
        for (int nf = 0; nf < 2; ++nf)
            b[nf] = *(const short8*)&Bs[(size_t)(lk * 64 + wn + nf * 16 + lm) * 8];
        #pragma unroll
        for (int mf = 0; mf < 4; ++mf)
            #pragma unroll
            for (int nf = 0; nf < 2; ++nf)
                acc[mf][nf] = __builtin_amdgcn_mfma_f32_16x16x32_bf16(
                    a[mf], b[nf], acc[mf][nf], 0, 0, 0);
    }
}

// =====================================================================
// k_cvt: fp32 -> bf16 elementwise (weights)
// =====================================================================
__global__ __launch_bounds__(256) void k_cvt(const float* __restrict__ s,
                                             uint16_t* __restrict__ d, int n) {
    int i = (blockIdx.x * 256 + threadIdx.x) * 4;
    if (i < n) {
        float4 v = *(const float4*)&s[i];
        ushort4 o;
        o.x = f_to_bf16(v.x); o.y = f_to_bf16(v.y);
        o.z = f_to_bf16(v.z); o.w = f_to_bf16(v.w);
        *(ushort4*)&d[i] = o;
    }
}

// =====================================================================
// k_xt: x[b][cf][t] fp32 -> xT[b][t][cf] bf16 (transpose + convert)
// =====================================================================
__global__ __launch_bounds__(256) void k_xt(const float* __restrict__ x,
                                            uint16_t* __restrict__ xT) {
    __shared__ float tile[64][65];
    const int b = blockIdx.z, cf0 = blockIdx.y * 64, t0 = blockIdx.x * 64;
    const int tid = threadIdx.x;
    #pragma unroll
    for (int p = 0; p < 4; ++p) {
        int cf_r = p * 16 + (tid >> 4);
        int t4   = (tid & 15) * 4;
        float4 v = *(const float4*)&x[((size_t)b * CF_ + cf0 + cf_r) * T_ + t0 + t4];
        tile[t4 + 0][cf_r] = v.x; tile[t4 + 1][cf_r] = v.y;
        tile[t4 + 2][cf_r] = v.z; tile[t4 + 3][cf_r] = v.w;
    }
    __syncthreads();
    #pragma unroll
    for (int p = 0; p < 4; ++p) {
        int t_r = p * 16 + (tid >> 4);
        int cf4 = (tid & 15) * 4;
        ushort4 o;
        o.x = f_to_bf16(tile[t_r][cf4 + 0]);
        o.y = f_to_bf16(tile[t_r][cf4 + 1]);
        o.z = f_to_bf16(tile[t_r][cf4 + 2]);
        o.w = f_to_bf16(tile[t_r][cf4 + 3]);
        *(ushort4*)&xT[((size_t)b * T_ + t0 + t_r) * CF_ + cf0 + cf4] = o;
    }
}

// =====================================================================
// k_fc1m: Hfc[b][t][d] bf16 = bf16( W_fc1(128x2048) @ x[b] + b_fc1 )
// A = W_fc1 bf16 (128xK), B = xT[b] (t x K). Grid (8 nt, 1, 32 b).
// =====================================================================
__global__ __launch_bounds__(256) void k_fc1m(const uint16_t* __restrict__ Wb,
                                              const uint16_t* __restrict__ xT,
                                              const float* __restrict__ bfc,
                                              uint16_t* __restrict__ Hfc) {
    __shared__ uint16_t As[4096], Bs[2048];
    const int b = blockIdx.z, n0 = blockIdx.x * 64;
    floatx4 acc[4][2] = {};
    gemm_core(Wb, xT + ((size_t)b * T_ + n0) * CF_, CF_, As, Bs, acc);
    const int tid = threadIdx.x, w = tid >> 6, l = tid & 63;
    const int wm = (w >> 1) * 64, wn = (w & 1) * 32, q = l >> 4, lm = l & 15;
    #pragma unroll
    for (int mf = 0; mf < 4; ++mf) {
        const int d0 = wm + mf * 16 + q * 4;
        const float4 bv = *(const float4*)&bfc[d0];
        #pragma unroll
        for (int nf = 0; nf < 2; ++nf) {
            const int t = n0 + wn + nf * 16 + lm;
            ushort4 o;
            o.x = f_to_bf16(acc[mf][nf][0] + bv.x);
            o.y = f_to_bf16(acc[mf][nf][1] + bv.y);
            o.z = f_to_bf16(acc[mf][nf][2] + bv.z);
            o.w = f_to_bf16(acc[mf][nf][3] + bv.w);
            *(ushort4*)&Hfc[((size_t)b * T_ + t) * H_ + d0] = o;
        }
    }
}

// =====================================================================
// k_xprojm: Xp[db][t][g] bf16 = bf16( Wih_dir @ Hfc[b]^T + b_dir )
// A = Wih (512g x 128), B = Hfc[b] (t x 128). Grid (8 nt, 4 mt, 64 db).
// =====================================================================
__global__ __launch_bounds__(256) void k_xprojm(const uint16_t* __restrict__ Wihb,
                                                const float* __restrict__ b_f,
                                                const float* __restrict__ b_b,
                                                const uint16_t* __restrict__ Hfc,
                                                uint16_t* __restrict__ Xp) {
    __shared__ uint16_t As[4096], Bs[2048];
    const int db = blockIdx.z, dir = db >> 5, b = db & 31;
    const int mt = blockIdx.y, n0 = blockIdx.x * 64;
    const uint16_t* Ap = Wihb + (size_t)dir * G4_ * H_ + (size_t)mt * 128 * H_;
    const float* bi = dir ? b_b : b_f;
    floatx4 acc[4][2] = {};
    gemm_core(Ap, Hfc + ((size_t)b * T_ + n0) * H_, H_, As, Bs, acc);
    const int tid = threadIdx.x, w = tid >> 6, l = tid & 63;
    const int wm = (w >> 1) * 64, wn = (w & 1) * 32, q = l >> 4, lm = l & 15;
    #pragma unroll
    for (int mf = 0; mf < 4; ++mf) {
        const int g0 = mt * 128 + wm + mf * 16 + q * 4;
        const float4 bv = *(const float4*)&bi[g0];
        #pragma unroll
        for (int nf = 0; nf < 2; ++nf) {
            const int t = n0 + wn + nf * 16 + lm;
            ushort4 o;
            o.x = f_to_bf16(acc[mf][nf][0] + bv.x);
            o.y = f_to_bf16(acc[mf][nf][1] + bv.y);
            o.z = f_to_bf16(acc[mf][nf][2] + bv.z);
            o.w = f_to_bf16(acc[mf][nf][3] + bv.w);
            *(ushort4*)&Xp[((size_t)db * T_ + t) * G4_ + g0] = o;
        }
    }
}

// =====================================================================
// k_lstm: unchanged recurrence (fp32 VALU), now writes hs in bf16.
// WG = 512 threads (one gate each), 4 t-frames, one dir.
// =====================================================================
__global__ __launch_bounds__(512) void k_lstm(const uint16_t* __restrict__ Xp,
                                              const float* __restrict__ Whh_f,
                                              const float* __restrict__ Whh_b,
                                              uint16_t* __restrict__ hs) {
    __shared__ float h_sh[4][H_];
    __shared__ float z_sh[4][G4_];
    const int dir = blockIdx.y;
    const int t0  = blockIdx.x * 4;
    const int g   = threadIdx.x;
    const float* Whh = dir ? Whh_b : Whh_f;

    float4 wr[32];
    #pragma unroll
    for (int i = 0; i < 32; ++i) wr[i] = *(const float4*)&Whh[(size_t)g * H_ + i * 4];

    const int hh  = threadIdx.x & (H_ - 1);
    const int tt2 = threadIdx.x >> 7;
    h_sh[tt2][hh] = 0.f;
    float c_reg = 0.f;
    __syncthreads();

    for (int s = 0; s < 32; ++s) {
        const int b_idx = dir ? (31 - s) : s;
        const uint16_t* xp = Xp + ((size_t)(dir * B_ + b_idx) * T_ + t0) * G4_ + g;
        float acc0 = bf16_to_f(xp[0]);
        float acc1 = bf16_to_f(xp[G4_]);
        float acc2 = bf16_to_f(xp[2 * G4_]);
        float acc3 = bf16_to_f(xp[3 * G4_]);
        #pragma unroll
        for (int d4 = 0; d4 < 32; ++d4) {
            float4 w  = wr[d4];
            float4 h0 = *(float4*)&h_sh[0][d4 * 4];
            float4 h1 = *(float4*)&h_sh[1][d4 * 4];
            float4 h2 = *(float4*)&h_sh[2][d4 * 4];
            float4 h3 = *(float4*)&h_sh[3][d4 * 4];
            acc0 += w.x * h0.x; acc0 += w.y * h0.y; acc0 += w.z * h0.z; acc0 += w.w * h0.w;
            acc1 += w.x * h1.x; acc1 += w.y * h1.y; acc1 += w.z * h1.z; acc1 += w.w * h1.w;
            acc2 += w.x * h2.x; acc2 += w.y * h2.y; acc2 += w.z * h2.z; acc2 += w.w * h2.w;
            acc3 += w.x * h3.x; acc3 += w.y * h3.y; acc3 += w.z * h3.z; acc3 += w.w * h3.w;
        }
        z_sh[0][g] = acc0; z_sh[1][g] = acc1; z_sh[2][g] = acc2; z_sh[3][g] = acc3;
        __syncthreads();
        float zi = z_sh[tt2][hh];
        float zf = z_sh[tt2][hh + 128];
        float zg = z_sh[tt2][hh + 256];
        float zo = z_sh[tt2][hh + 384];
        float si = 1.f / (1.f + __expf(-zi));
        float sf = 1.f / (1.f + __expf(-zf));
        float so = 1.f / (1.f + __expf(-zo));
        float eg = __expf(2.f * zg);
        float tg = 1.f - 2.f / (eg + 1.f);
        c_reg = sf * c_reg + si * tg;
        float ec = __expf(2.f * c_reg);
        float tc = 1.f - 2.f / (ec + 1.f);
        float hn = so * tc;
        h_sh[tt2][hh] = hn;
        hs[((size_t)b_idx * T_ + t0 + tt2) * 256 + dir * H_ + hh] = f_to_bf16(hn);
        __syncthreads();
    }
}

// =====================================================================
// k_outm: out[b][e][t] fp32 = W_out(128x256) @ hs[b]^T + b_out
// A = W_out bf16, B = hs[b] (t x 256) bf16. Grid (8 nt, 1, 32 b).
// =====================================================================
__global__ __launch_bounds__(256) void k_outm(const uint16_t* __restrict__ Woutb,
                                              const uint16_t* __restrict__ hs,
                                              const float* __restrict__ bout,
                                              float* __restrict__ out) {
    __shared__ uint16_t As[4096], Bs[2048];
    const int b = blockIdx.z, n0 = blockIdx.x * 64;
    floatx4 acc[4][2] = {};
    gemm_core(Woutb, hs + ((size_t)b * T_ + n0) * 256, 256, As, Bs, acc);
    const int tid = threadIdx.x, w = tid >> 6, l = tid & 63;
    const int wm = (w >> 1) * 64, wn = (w & 1) * 32, q = l >> 4, lm = l & 15;
    #pragma unroll
    for (int mf = 0; mf < 4; ++mf) {
        const int e0 = wm + mf * 16 + q * 4;
        const float4 bv = *(const float4*)&bout[e0];
        #pragma unroll
        for (int nf = 0; nf < 2; ++nf) {
            const int t = n0 + wn + nf * 16 + lm;
            out[((size_t)b * H_ + e0 + 0) * T_ + t] = acc[mf][nf][0] + bv.x;
            out[((size_t)b * H_ + e0 + 1) * T_ + t] = acc[mf][nf][1] + bv.y;
            out[((size_t)b * H_ + e0 + 2) * T_ + t] = acc[mf][nf][2] + bv.z;
            out[((size_t)b * H_ + e0 + 3) * T_ + t] = acc[mf][nf][3] + bv.w;
        }
    }
}

// =====================================================================
extern "C" void kernel_launch(void* const* d_in, const int* in_sizes, int n_in,
                              void* d_out, int out_size, void* d_ws, size_t ws_size,
                              hipStream_t stream) {
    const float* x     = (const float*)d_in[0];
    const float* Wfc   = (const float*)d_in[1];
    const float* bfc   = (const float*)d_in[2];
    const float* Wih_f = (const float*)d_in[3];
    const float* Whh_f = (const float*)d_in[4];
    const float* b_f   = (const float*)d_in[5];
    const float* Wih_b = (const float*)d_in[6];
    const float* Whh_b = (const float*)d_in[7];
    const float* b_b   = (const float*)d_in[8];
    const float* Wout  = (const float*)d_in[9];
    const float* bout  = (const float*)d_in[10];
    float* out = (float*)d_out;

    char* ws = (char*)d_ws;
    uint16_t* xT    = (uint16_t*)(ws);                        //  67,108,864 B
    uint16_t* HfcB  = (uint16_t*)(ws + 67108864);             //   8,388,608 B
    uint16_t* Xp    = (uint16_t*)(ws + 75497472);             //  33,554,432 B
    uint16_t* hsB   = (uint16_t*)(ws + 109051904);            //   8,388,608 B
    uint16_t* WfcB  = (uint16_t*)(ws + 117440512);            //     524,288 B
    uint16_t* WihB  = (uint16_t*)(ws + 117964800);            //     262,144 B (both dirs)
    uint16_t* WoutB = (uint16_t*)(ws + 118226944);            //      65,536 B
                                                              // total ~113 MB

    k_cvt<<<dim3(256), 256, 0, stream>>>(Wfc,   WfcB,          262144);
    k_cvt<<<dim3(64),  256, 0, stream>>>(Wih_f, WihB,           65536);
    k_cvt<<<dim3(64),  256, 0, stream>>>(Wih_b, WihB + 65536,   65536);
    k_cvt<<<dim3(32),  256, 0, stream>>>(Wout,  WoutB,          32768);
    k_xt   <<<dim3(8, 32, 32), 256, 0, stream>>>(x, xT);
    k_fc1m <<<dim3(8, 1, 32),  256, 0, stream>>>(WfcB, xT, bfc, HfcB);
    k_xprojm<<<dim3(8, 4, 64), 256, 0, stream>>>(WihB, b_f, b_b, HfcB, Xp);
    k_lstm <<<dim3(128, 2),    512, 0, stream>>>(Xp, Whh_f, Whh_b, hsB);
    k_outm <<<dim3(8, 1, 32),  256, 0, stream>>>(WoutB, hsB, bout, out);
}

// Round 3
// 341.626 us; speedup vs baseline: 1.4184x; 1.1701x over previous
//
#include <hip/hip_runtime.h>
#include <stdint.h>

typedef __attribute__((ext_vector_type(8))) short short8;
typedef __attribute__((ext_vector_type(4))) float floatx4;

// ---------- helpers ----------
__device__ __forceinline__ float bf16_to_f(uint16_t u) {
    union { uint32_t i; float f; } v; v.i = ((uint32_t)u) << 16; return v.f;
}
__device__ __forceinline__ uint16_t f_to_bf16(float f) {
    union { uint32_t i; float f; } v; v.f = f;
    uint32_t u = v.i;
    u += 0x7FFFu + ((u >> 16) & 1u);   // round-to-nearest-even
    return (uint16_t)(u >> 16);
}
__device__ __forceinline__ void gload16(const void* g, void* l) {
    __builtin_amdgcn_global_load_lds(
        (const __attribute__((address_space(1))) void*)g,
        (__attribute__((address_space(3))) void*)l, 16, 0, 0);
}
__device__ __forceinline__ float rcpf(float x) { return __builtin_amdgcn_rcpf(x); }

#define B_  32
#define T_  512
#define CF_ 2048
#define H_  128
#define G4_ 512   // 4*H
#define LOG2E 1.4426950408889634f

// =====================================================================
// gemm64: C(64x64) += A(64xK) * B(64xK)^T, bf16, BK=64, 256 thr / 4 waves.
// Wave w: 32x32 quadrant (wm=(w>>1)*32, wn=(w&1)*32), 2x2 frags 16x16x32.
// LDS k-chunk-major: chunk c (k in [c*8,c*8+8)) row r at shorts (c*64+r)*8.
// Satisfies global_load_lds "uniform base + lane*16"; frag ds_read_b128
// 2-way bank aliasing only (free).
// =====================================================================
__device__ __forceinline__ void gemm64(const uint16_t* __restrict__ A,
                                       const uint16_t* __restrict__ B,
                                       int K, uint16_t* As, uint16_t* Bs,
                                       floatx4 acc[2][2]) {
    const int tid = threadIdx.x, w = tid >> 6, l = tid & 63;
    const int wm = (w >> 1) * 32, wn = (w & 1) * 32;
    const int lm = l & 15, lk = l >> 4;
    const uint16_t* gA = A + (size_t)l * K;
    const uint16_t* gB = B + (size_t)l * K;
    uint16_t* dA0 = As + ((2 * w) * 64 + l) * 8;
    uint16_t* dA1 = As + ((2 * w + 1) * 64 + l) * 8;
    uint16_t* dB0 = Bs + ((2 * w) * 64 + l) * 8;
    uint16_t* dB1 = Bs + ((2 * w + 1) * 64 + l) * 8;
    for (int k0 = 0; k0 < K; k0 += 64) {
        __syncthreads();
        gload16(gA + k0 + (2 * w) * 8,     dA0);
        gload16(gA + k0 + (2 * w + 1) * 8, dA1);
        gload16(gB + k0 + (2 * w) * 8,     dB0);
        gload16(gB + k0 + (2 * w + 1) * 8, dB1);
        __syncthreads();
        short8 a[2][2], b[2][2];
        #pragma unroll
        for (int kf = 0; kf < 2; ++kf) {
            #pragma unroll
            for (int mf = 0; mf < 2; ++mf)
                a[mf][kf] = *(const short8*)&As[(size_t)((kf * 4 + lk) * 64 + wm + mf * 16 + lm) * 8];
            #pragma unroll
            for (int nf = 0; nf < 2; ++nf)
                b[nf][kf] = *(const short8*)&Bs[(size_t)((kf * 4 + lk) * 64 + wn + nf * 16 + lm) * 8];
        }
        #pragma unroll
        for (int mf = 0; mf < 2; ++mf)
            #pragma unroll
            for (int nf = 0; nf < 2; ++nf) {
                acc[mf][nf] = __builtin_amdgcn_mfma_f32_16x16x32_bf16(a[mf][0], b[nf][0], acc[mf][nf], 0, 0, 0);
                acc[mf][nf] = __builtin_amdgcn_mfma_f32_16x16x32_bf16(a[mf][1], b[nf][1], acc[mf][nf], 0, 0, 0);
            }
    }
}

// =====================================================================
// k_cvt_all: all 6 weight tensors fp32 -> bf16 in ONE launch.
// block ranges: Wfc 256 | Wih_f 64 | Wih_b 64 | Whh_f 64 | Whh_b 64 | Wout 32
// =====================================================================
__global__ __launch_bounds__(256) void k_cvt_all(
        const float* __restrict__ Wfc, const float* __restrict__ Wih_f,
        const float* __restrict__ Wih_b, const float* __restrict__ Whh_f,
        const float* __restrict__ Whh_b, const float* __restrict__ Wout,
        uint16_t* __restrict__ WfcB, uint16_t* __restrict__ WihB,
        uint16_t* __restrict__ WhhB, uint16_t* __restrict__ WoutB) {
    const int blk = blockIdx.x;
    const float* s; uint16_t* d; int off;
    if (blk < 256)      { s = Wfc;   d = WfcB;          off = blk; }
    else if (blk < 320) { s = Wih_f; d = WihB;          off = blk - 256; }
    else if (blk < 384) { s = Wih_b; d = WihB + 65536;  off = blk - 320; }
    else if (blk < 448) { s = Whh_f; d = WhhB;          off = blk - 384; }
    else if (blk < 512) { s = Whh_b; d = WhhB + 65536;  off = blk - 448; }
    else                { s = Wout;  d = WoutB;         off = blk - 512; }
    const int i = off * 1024 + threadIdx.x * 4;
    float4 v = *(const float4*)&s[i];
    ushort4 o;
    o.x = f_to_bf16(v.x); o.y = f_to_bf16(v.y);
    o.z = f_to_bf16(v.z); o.w = f_to_bf16(v.w);
    *(ushort4*)&d[i] = o;
}

// =====================================================================
// k_xt: x[b][cf][t] fp32 -> xT[b][t][cf] bf16 (transpose + convert)
// =====================================================================
__global__ __launch_bounds__(256) void k_xt(const float* __restrict__ x,
                                            uint16_t* __restrict__ xT) {
    __shared__ float tile[64][65];
    const int b = blockIdx.z, cf0 = blockIdx.y * 64, t0 = blockIdx.x * 64;
    const int tid = threadIdx.x;
    #pragma unroll
    for (int p = 0; p < 4; ++p) {
        int cf_r = p * 16 + (tid >> 4);
        int t4   = (tid & 15) * 4;
        float4 v = *(const float4*)&x[((size_t)b * CF_ + cf0 + cf_r) * T_ + t0 + t4];
        tile[t4 + 0][cf_r] = v.x; tile[t4 + 1][cf_r] = v.y;
        tile[t4 + 2][cf_r] = v.z; tile[t4 + 3][cf_r] = v.w;
    }
    __syncthreads();
    #pragma unroll
    for (int p = 0; p < 4; ++p) {
        int t_r = p * 16 + (tid >> 4);
        int cf4 = (tid & 15) * 4;
        ushort4 o;
        o.x = f_to_bf16(tile[t_r][cf4 + 0]);
        o.y = f_to_bf16(tile[t_r][cf4 + 1]);
        o.z = f_to_bf16(tile[t_r][cf4 + 2]);
        o.w = f_to_bf16(tile[t_r][cf4 + 3]);
        *(ushort4*)&xT[((size_t)b * T_ + t0 + t_r) * CF_ + cf0 + cf4] = o;
    }
}

// =====================================================================
// k_fc1m: Hfc[b][t][d] bf16 = bf16( W_fc1 @ x[b] + b_fc1 )
// grid (T/64=8, 128/64=2, 32)
// =====================================================================
__global__ __launch_bounds__(256) void k_fc1m(const uint16_t* __restrict__ Wb,
                                              const uint16_t* __restrict__ xT,
                                              const float* __restrict__ bfc,
                                              uint16_t* __restrict__ Hfc) {
    __shared__ __align__(16) uint16_t As[4096], Bs[4096];
    const int b = blockIdx.z, m0 = blockIdx.y * 64, n0 = blockIdx.x * 64;
    floatx4 acc[2][2] = {};
    gemm64(Wb + (size_t)m0 * CF_, xT + ((size_t)b * T_ + n0) * CF_, CF_, As, Bs, acc);
    const int tid = threadIdx.x, w = tid >> 6, l = tid & 63;
    const int wm = (w >> 1) * 32, wn = (w & 1) * 32, lm = l & 15, lk = l >> 4;
    #pragma unroll
    for (int mf = 0; mf < 2; ++mf) {
        const int d0 = m0 + wm + mf * 16 + lk * 4;
        const float4 bv = *(const float4*)&bfc[d0];
        #pragma unroll
        for (int nf = 0; nf < 2; ++nf) {
            const int t = n0 + wn + nf * 16 + lm;
            ushort4 o;
            o.x = f_to_bf16(acc[mf][nf][0] + bv.x);
            o.y = f_to_bf16(acc[mf][nf][1] + bv.y);
            o.z = f_to_bf16(acc[mf][nf][2] + bv.z);
            o.w = f_to_bf16(acc[mf][nf][3] + bv.w);
            *(ushort4*)&Hfc[((size_t)b * T_ + t) * H_ + d0] = o;
        }
    }
}

// =====================================================================
// k_xprojm: Xp[db][t][g] bf16 = bf16( Wih_dir @ Hfc[b]^T + b_dir )
// grid (T/64=8, 512/64=8, 64 db)
// =====================================================================
__global__ __launch_bounds__(256) void k_xprojm(const uint16_t* __restrict__ WihB,
                                                const float* __restrict__ b_f,
                                                const float* __restrict__ b_b,
                                                const uint16_t* __restrict__ Hfc,
                                                uint16_t* __restrict__ Xp) {
    __shared__ __align__(16) uint16_t As[4096], Bs[4096];
    const int db = blockIdx.z, dir = db >> 5, b = db & 31;
    const int g0 = blockIdx.y * 64, n0 = blockIdx.x * 64;
    const float* bi = dir ? b_b : b_f;
    floatx4 acc[2][2] = {};
    gemm64(WihB + ((size_t)dir * G4_ + g0) * H_, Hfc + ((size_t)b * T_ + n0) * H_, H_, As, Bs, acc);
    const int tid = threadIdx.x, w = tid >> 6, l = tid & 63;
    const int wm = (w >> 1) * 32, wn = (w & 1) * 32, lm = l & 15, lk = l >> 4;
    #pragma unroll
    for (int mf = 0; mf < 2; ++mf) {
        const int g_ = g0 + wm + mf * 16 + lk * 4;
        const float4 bv = *(const float4*)&bi[g_];
        #pragma unroll
        for (int nf = 0; nf < 2; ++nf) {
            const int t = n0 + wn + nf * 16 + lm;
            ushort4 o;
            o.x = f_to_bf16(acc[mf][nf][0] + bv.x);
            o.y = f_to_bf16(acc[mf][nf][1] + bv.y);
            o.z = f_to_bf16(acc[mf][nf][2] + bv.z);
            o.w = f_to_bf16(acc[mf][nf][3] + bv.w);
            *(ushort4*)&Xp[((size_t)db * T_ + t) * G4_ + g_] = o;
        }
    }
}

// =====================================================================
// k_lstm: MFMA recurrence. WG = (dir, 16 t-frames), 512 thr = 8 waves.
// Wave w owns g-slab [w*64, w*64+64): 4 N-tiles, 4 K-frags; Whh B-frags
// persist in 64 VGPRs. h (16x128 bf16) in LDS (row stride 136 shorts);
// z (16x512 f32) LDS roundtrip (row stride 516). Gate combine: thread ->
// (hh = tid&127, 4 t), c state in regs, v_rcp/v_exp gates.
// =====================================================================
__global__ __launch_bounds__(512) void k_lstm(const uint16_t* __restrict__ Xp,
                                              const uint16_t* __restrict__ WhhB,
                                              uint16_t* __restrict__ hs) {
    __shared__ __align__(16) uint16_t h_sh[16 * 136];
    __shared__ float z_sh[16 * 516];
    const int dir = blockIdx.y, t0 = blockIdx.x * 16;
    const int tid = threadIdx.x, w = tid >> 6, l = tid & 63;
    const int lm = l & 15, lk = l >> 4;
    const int gw = w * 64;
    const uint16_t* Wp = WhhB + dir * (G4_ * H_);

    short8 bw[4][4];
    #pragma unroll
    for (int nf = 0; nf < 4; ++nf)
        #pragma unroll
        for (int kf = 0; kf < 4; ++kf)
            bw[nf][kf] = *(const short8*)&Wp[(size_t)(gw + nf * 16 + lm) * H_ + kf * 32 + lk * 8];

    for (int i = tid; i < 16 * 136; i += 512) h_sh[i] = 0;
    const int hh = tid & 127, tq = tid >> 7;
    float c[4] = {0.f, 0.f, 0.f, 0.f};
    __syncthreads();

    for (int s = 0; s < 32; ++s) {
        const int b_idx = dir ? (31 - s) : s;
        const uint16_t* xp = Xp + ((size_t)(dir * B_ + b_idx) * T_ + t0) * G4_;
        // prefetch Xp for the gate phase (drained by mid-barrier)
        uint16_t xv[4][4];
        #pragma unroll
        for (int j = 0; j < 4; ++j)
            #pragma unroll
            for (int gg = 0; gg < 4; ++gg)
                xv[j][gg] = xp[(size_t)(tq * 4 + j) * G4_ + gg * H_ + hh];

        // ---- MFMA phase: z[t][g] = h @ Whh^T ----
        short8 af[4];
        #pragma unroll
        for (int kf = 0; kf < 4; ++kf)
            af[kf] = *(const short8*)&h_sh[lm * 136 + kf * 32 + lk * 8];
        floatx4 acc[4] = {};
        #pragma unroll
        for (int nf = 0; nf < 4; ++nf)
            #pragma unroll
            for (int kf = 0; kf < 4; ++kf)
                acc[nf] = __builtin_amdgcn_mfma_f32_16x16x32_bf16(af[kf], bw[nf][kf], acc[nf], 0, 0, 0);
        #pragma unroll
        for (int nf = 0; nf < 4; ++nf)
            #pragma unroll
            for (int r = 0; r < 4; ++r)
                z_sh[(lk * 4 + r) * 516 + gw + nf * 16 + lm] = acc[nf][r];
        __syncthreads();

        // ---- gate phase ----
        #pragma unroll
        for (int j = 0; j < 4; ++j) {
            const int t = tq * 4 + j;
            const float* zr = &z_sh[t * 516];
            float zi = zr[hh]            + bf16_to_f(xv[j][0]);
            float zf = zr[H_ + hh]       + bf16_to_f(xv[j][1]);
            float zg = zr[2 * H_ + hh]   + bf16_to_f(xv[j][2]);
            float zo = zr[3 * H_ + hh]   + bf16_to_f(xv[j][3]);
            float si = rcpf(1.f + __builtin_amdgcn_exp2f(-LOG2E * zi));
            float sf = rcpf(1.f + __builtin_amdgcn_exp2f(-LOG2E * zf));
            float so = rcpf(1.f + __builtin_amdgcn_exp2f(-LOG2E * zo));
            float tg = 1.f - 2.f * rcpf(1.f + __builtin_amdgcn_exp2f(2.f * LOG2E * zg));
            c[j] = sf * c[j] + si * tg;
            float tc = 1.f - 2.f * rcpf(1.f + __builtin_amdgcn_exp2f(2.f * LOG2E * c[j]));
            float hn = so * tc;
            uint16_t hb = f_to_bf16(hn);
            h_sh[t * 136 + hh] = hb;
            hs[((size_t)b_idx * T_ + t0 + t) * 256 + dir * H_ + hh] = hb;
        }
        __syncthreads();
    }
}

// =====================================================================
// k_outm: out[b][e][t] fp32 = W_out(128x256) @ hs[b]^T + b_out
// grid (8, 2, 32)
// =====================================================================
__global__ __launch_bounds__(256) void k_outm(const uint16_t* __restrict__ WoutB,
                                              const uint16_t* __restrict__ hs,
                                              const float* __restrict__ bout,
                                              float* __restrict__ out) {
    __shared__ __align__(16) uint16_t As[4096], Bs[4096];
    const int b = blockIdx.z, m0 = blockIdx.y * 64, n0 = blockIdx.x * 64;
    floatx4 acc[2][2] = {};
    gemm64(WoutB + (size_t)m0 * 256, hs + ((size_t)b * T_ + n0) * 256, 256, As, Bs, acc);
    const int tid = threadIdx.x, w = tid >> 6, l = tid & 63;
    const int wm = (w >> 1) * 32, wn = (w & 1) * 32, lm = l & 15, lk = l >> 4;
    #pragma unroll
    for (int mf = 0; mf < 2; ++mf) {
        const int e0 = m0 + wm + mf * 16 + lk * 4;
        const float4 bv = *(const float4*)&bout[e0];
        #pragma unroll
        for (int nf = 0; nf < 2; ++nf) {
            const int t = n0 + wn + nf * 16 + lm;
            out[((size_t)b * H_ + e0 + 0) * T_ + t] = acc[mf][nf][0] + bv.x;
            out[((size_t)b * H_ + e0 + 1) * T_ + t] = acc[mf][nf][1] + bv.y;
            out[((size_t)b * H_ + e0 + 2) * T_ + t] = acc[mf][nf][2] + bv.z;
            out[((size_t)b * H_ + e0 + 3) * T_ + t] = acc[mf][nf][3] + bv.w;
        }
    }
}

// =====================================================================
extern "C" void kernel_launch(void* const* d_in, const int* in_sizes, int n_in,
                              void* d_out, int out_size, void* d_ws, size_t ws_size,
                              hipStream_t stream) {
    const float* x     = (const float*)d_in[0];
    const float* Wfc   = (const float*)d_in[1];
    const float* bfc   = (const float*)d_in[2];
    const float* Wih_f = (const float*)d_in[3];
    const float* Whh_f = (const float*)d_in[4];
    const float* b_f   = (const float*)d_in[5];
    const float* Wih_b = (const float*)d_in[6];
    const float* Whh_b = (const float*)d_in[7];
    const float* b_b   = (const float*)d_in[8];
    const float* Wout  = (const float*)d_in[9];
    const float* bout  = (const float*)d_in[10];
    float* out = (float*)d_out;

    char* ws = (char*)d_ws;
    uint16_t* xT    = (uint16_t*)(ws);                        // 67,108,864 B
    uint16_t* HfcB  = (uint16_t*)(ws + 67108864);             //  8,388,608 B
    uint16_t* Xp    = (uint16_t*)(ws + 75497472);             // 33,554,432 B
    uint16_t* hsB   = (uint16_t*)(ws + 109051904);            //  8,388,608 B
    uint16_t* WfcB  = (uint16_t*)(ws + 117440512);            //    524,288 B
    uint16_t* WihB  = (uint16_t*)(ws + 117964800);            //    262,144 B
    uint16_t* WhhB  = (uint16_t*)(ws + 118226944);            //    262,144 B
    uint16_t* WoutB = (uint16_t*)(ws + 118489088);            //     65,536 B

    k_cvt_all<<<dim3(544), 256, 0, stream>>>(Wfc, Wih_f, Wih_b, Whh_f, Whh_b, Wout,
                                             WfcB, WihB, WhhB, WoutB);
    k_xt    <<<dim3(8, 32, 32), 256, 0, stream>>>(x, xT);
    k_fc1m  <<<dim3(8, 2, 32),  256, 0, stream>>>(WfcB, xT, bfc, HfcB);
    k_xprojm<<<dim3(8, 8, 64),  256, 0, stream>>>(WihB, b_f, b_b, HfcB, Xp);
    k_lstm  <<<dim3(32, 2),     512, 0, stream>>>(Xp, WhhB, hsB);
    k_outm  <<<dim3(8, 2, 32),  256, 0, stream>>>(WoutB, hsB, bout, out);
}

// Round 4
// 298.917 us; speedup vs baseline: 1.6211x; 1.1429x over previous
//
#include <hip/hip_runtime.h>
#include <stdint.h>

typedef __attribute__((ext_vector_type(8))) short short8;
typedef __attribute__((ext_vector_type(4))) float floatx4;

// ---------- helpers ----------
__device__ __forceinline__ float bf16_to_f(uint16_t u) {
    union { uint32_t i; float f; } v; v.i = ((uint32_t)u) << 16; return v.f;
}
__device__ __forceinline__ uint16_t f_to_bf16(float f) {
    union { uint32_t i; float f; } v; v.f = f;
    uint32_t u = v.i;
    u += 0x7FFFu + ((u >> 16) & 1u);   // round-to-nearest-even
    return (uint16_t)(u >> 16);
}
__device__ __forceinline__ void gload16(const void* g, void* l) {
    __builtin_amdgcn_global_load_lds(
        (const __attribute__((address_space(1))) void*)g,
        (__attribute__((address_space(3))) void*)l, 16, 0, 0);
}
__device__ __forceinline__ float rcpf(float x) { return __builtin_amdgcn_rcpf(x); }

#define B_  32
#define T_  512
#define CF_ 2048
#define H_  128
#define G4_ 512   // 4*H
#define LOG2E 1.4426950408889634f

// =====================================================================
// k_cvt_all: all 6 weight tensors fp32 -> bf16 in ONE launch.
// =====================================================================
__global__ __launch_bounds__(256) void k_cvt_all(
        const float* __restrict__ Wfc, const float* __restrict__ Wih_f,
        const float* __restrict__ Wih_b, const float* __restrict__ Whh_f,
        const float* __restrict__ Whh_b, const float* __restrict__ Wout,
        uint16_t* __restrict__ WfcB, uint16_t* __restrict__ WihB,
        uint16_t* __restrict__ WhhB, uint16_t* __restrict__ WoutB) {
    const int blk = blockIdx.x;
    const float* s; uint16_t* d; int off;
    if (blk < 256)      { s = Wfc;   d = WfcB;          off = blk; }
    else if (blk < 320) { s = Wih_f; d = WihB;          off = blk - 256; }
    else if (blk < 384) { s = Wih_b; d = WihB + 65536;  off = blk - 320; }
    else if (blk < 448) { s = Whh_f; d = WhhB;          off = blk - 384; }
    else if (blk < 512) { s = Whh_b; d = WhhB + 65536;  off = blk - 448; }
    else                { s = Wout;  d = WoutB;         off = blk - 512; }
    const int i = off * 1024 + threadIdx.x * 4;
    float4 v = *(const float4*)&s[i];
    ushort4 o;
    o.x = f_to_bf16(v.x); o.y = f_to_bf16(v.y);
    o.z = f_to_bf16(v.z); o.w = f_to_bf16(v.w);
    *(ushort4*)&d[i] = o;
}

// =====================================================================
// k_fc1x: fused  x-transpose + fc1 + input-projection.
// Grid (T/64=8, B=32), 512 thr = 8 waves, 1 WG/CU.
// Phase A: Hfc_tile(128d x 64t) = W_fc1(128x2048) @ x[b](2048 x t-tile)
//   x fp32 -> LDS transpose tile (stride 65, scalar rw = 2-way free)
//   -> bf16 chunk-major Bs. W_fc1 via global_load_lds. Result -> LDS Hs2.
// Phase B: Xp[dir][t][g] = Wih_dir @ Hfc_tile^T + b_dir, Wih frags from
//   global (L2-hot). Wave w: dir=w>>2, g-slab (w&3)*64 (+256 per it).
// =====================================================================
__global__ __launch_bounds__(512) void k_fc1x(const float* __restrict__ x,
                                              const uint16_t* __restrict__ WfcB,
                                              const float* __restrict__ bfc,
                                              const uint16_t* __restrict__ WihB,
                                              const float* __restrict__ b_f,
                                              const float* __restrict__ b_b,
                                              uint16_t* __restrict__ Xp) {
    __shared__ float tile[64 * 65];                    // [t][cf] fp32
    __shared__ __align__(16) uint16_t As[8192];        // W chunk-major
    __shared__ __align__(16) uint16_t Bs[4224];        // xT chunk-major (stride 66)
    __shared__ __align__(16) uint16_t Hs2[8432];       // Hfc chunk-major (stride 66)

    const int bb = blockIdx.y, n0 = blockIdx.x * 64;
    const int tid = threadIdx.x, w = tid >> 6, l = tid & 63;
    const int lm = l & 15, lk = l >> 4;
    const float* xb = x + (size_t)bb * CF_ * T_;

    // stage-1 mapping (x load / tile write)
    const int t4 = (tid & 15) * 4, cf_r = tid >> 4;    // cf_r in 0..31 (+32)
    // stage-2 mapping (tile read / Bs write)
    const int kk = (tid & 15) * 4, t_r = tid >> 4;     // t_r in 0..31 (+32)

    float4 xv0, xv1;
    {
        const float* p = &xb[(size_t)(0 + cf_r) * T_ + n0 + t4];
        xv0 = *(const float4*)p;
        xv1 = *(const float4*)(p + 32 * T_);
    }

    // ---------------- Phase A ----------------
    const int wmA = (w >> 1) * 32, wnA = (w & 1) * 32;
    floatx4 acc[2][2] = {};
    for (int k0 = 0; k0 < CF_; k0 += 64) {
        __syncthreads();
        // stage1: fp32 transpose tile
        tile[(t4 + 0) * 65 + cf_r] = xv0.x;
        tile[(t4 + 1) * 65 + cf_r] = xv0.y;
        tile[(t4 + 2) * 65 + cf_r] = xv0.z;
        tile[(t4 + 3) * 65 + cf_r] = xv0.w;
        tile[(t4 + 0) * 65 + cf_r + 32] = xv1.x;
        tile[(t4 + 1) * 65 + cf_r + 32] = xv1.y;
        tile[(t4 + 2) * 65 + cf_r + 32] = xv1.z;
        tile[(t4 + 3) * 65 + cf_r + 32] = xv1.w;
        // A staging: wave w stages chunk w (k-offset w*8), rows l and 64+l
        gload16(WfcB + (size_t)l * CF_ + k0 + w * 8,        As + (w * 128 + l) * 8);
        gload16(WfcB + (size_t)(64 + l) * CF_ + k0 + w * 8, As + (w * 128 + 64 + l) * 8);
        __syncthreads();
        // prefetch next x block
        if (k0 + 64 < CF_) {
            const float* p = &xb[(size_t)(k0 + 64 + cf_r) * T_ + n0 + t4];
            xv0 = *(const float4*)p;
            xv1 = *(const float4*)(p + 32 * T_);
        }
        // stage2: tile -> bf16 chunk-major Bs
        #pragma unroll
        for (int pass = 0; pass < 2; ++pass) {
            const int tr = t_r + pass * 32;
            ushort4 o;
            o.x = f_to_bf16(tile[tr * 65 + kk + 0]);
            o.y = f_to_bf16(tile[tr * 65 + kk + 1]);
            o.z = f_to_bf16(tile[tr * 65 + kk + 2]);
            o.w = f_to_bf16(tile[tr * 65 + kk + 3]);
            *(ushort4*)&Bs[((kk >> 3) * 66 + tr) * 8 + (kk & 7)] = o;
        }
        __syncthreads();
        // frags + MFMA
        short8 a[2][2], bfr[2][2];
        #pragma unroll
        for (int kf = 0; kf < 2; ++kf) {
            #pragma unroll
            for (int mf = 0; mf < 2; ++mf)
                a[mf][kf] = *(const short8*)&As[((kf * 4 + lk) * 128 + wmA + mf * 16 + lm) * 8];
            #pragma unroll
            for (int nf = 0; nf < 2; ++nf)
                bfr[nf][kf] = *(const short8*)&Bs[((kf * 4 + lk) * 66 + wnA + nf * 16 + lm) * 8];
        }
        #pragma unroll
        for (int mf = 0; mf < 2; ++mf)
            #pragma unroll
            for (int nf = 0; nf < 2; ++nf) {
                acc[mf][nf] = __builtin_amdgcn_mfma_f32_16x16x32_bf16(a[mf][0], bfr[nf][0], acc[mf][nf], 0, 0, 0);
                acc[mf][nf] = __builtin_amdgcn_mfma_f32_16x16x32_bf16(a[mf][1], bfr[nf][1], acc[mf][nf], 0, 0, 0);
            }
    }
    __syncthreads();
    // epilogue A: bias + bf16 -> Hs2 chunk-major (stride 66)
    #pragma unroll
    for (int mf = 0; mf < 2; ++mf) {
        const int d0 = wmA + mf * 16 + lk * 4;
        const float4 bv = *(const float4*)&bfc[d0];
        const int c = ((wmA + mf * 16) >> 3) + (lk >> 1);
        #pragma unroll
        for (int nf = 0; nf < 2; ++nf) {
            const int t = wnA + nf * 16 + lm;
            ushort4 o;
            o.x = f_to_bf16(acc[mf][nf][0] + bv.x);
            o.y = f_to_bf16(acc[mf][nf][1] + bv.y);
            o.z = f_to_bf16(acc[mf][nf][2] + bv.z);
            o.w = f_to_bf16(acc[mf][nf][3] + bv.w);
            *(ushort4*)&Hs2[(c * 66 + t) * 8 + (lk & 1) * 4] = o;
        }
    }
    __syncthreads();

    // ---------------- Phase B ----------------
    const int dirw = w >> 2;
    const int db   = dirw * B_ + bb;
    const uint16_t* Wp = WihB + (size_t)dirw * (G4_ * H_);
    const float* bi = dirw ? b_b : b_f;
    #pragma unroll
    for (int it = 0; it < 2; ++it) {
        const int gbase = (w & 3) * 64 + it * 256;
        short8 aw[4][4];
        #pragma unroll
        for (int mf = 0; mf < 4; ++mf)
            #pragma unroll
            for (int kf = 0; kf < 4; ++kf)
                aw[mf][kf] = *(const short8*)&Wp[(size_t)(gbase + mf * 16 + lm) * H_ + kf * 32 + lk * 8];
        floatx4 acc2[4][4] = {};
        #pragma unroll
        for (int nf = 0; nf < 4; ++nf) {
            short8 bbf[4];
            #pragma unroll
            for (int kf = 0; kf < 4; ++kf)
                bbf[kf] = *(const short8*)&Hs2[((kf * 4 + lk) * 66 + nf * 16 + lm) * 8];
            #pragma unroll
            for (int mf = 0; mf < 4; ++mf)
                #pragma unroll
                for (int kf = 0; kf < 4; ++kf)
                    acc2[mf][nf] = __builtin_amdgcn_mfma_f32_16x16x32_bf16(aw[mf][kf], bbf[kf], acc2[mf][nf], 0, 0, 0);
        }
        #pragma unroll
        for (int mf = 0; mf < 4; ++mf) {
            const int g0 = gbase + mf * 16 + lk * 4;
            const float4 bv = *(const float4*)&bi[g0];
            #pragma unroll
            for (int nf = 0; nf < 4; ++nf) {
                const int t = n0 + nf * 16 + lm;
                ushort4 o;
                o.x = f_to_bf16(acc2[mf][nf][0] + bv.x);
                o.y = f_to_bf16(acc2[mf][nf][1] + bv.y);
                o.z = f_to_bf16(acc2[mf][nf][2] + bv.z);
                o.w = f_to_bf16(acc2[mf][nf][3] + bv.w);
                *(ushort4*)&Xp[((size_t)db * T_ + t) * G4_ + g0] = o;
            }
        }
    }
}

// =====================================================================
// k_lstm: MFMA recurrence (unchanged from round 3).
// =====================================================================
__global__ __launch_bounds__(512) void k_lstm(const uint16_t* __restrict__ Xp,
                                              const uint16_t* __restrict__ WhhB,
                                              uint16_t* __restrict__ hs) {
    __shared__ __align__(16) uint16_t h_sh[16 * 136];
    __shared__ float z_sh[16 * 516];
    const int dir = blockIdx.y, t0 = blockIdx.x * 16;
    const int tid = threadIdx.x, w = tid >> 6, l = tid & 63;
    const int lm = l & 15, lk = l >> 4;
    const int gw = w * 64;
    const uint16_t* Wp = WhhB + dir * (G4_ * H_);

    short8 bw[4][4];
    #pragma unroll
    for (int nf = 0; nf < 4; ++nf)
        #pragma unroll
        for (int kf = 0; kf < 4; ++kf)
            bw[nf][kf] = *(const short8*)&Wp[(size_t)(gw + nf * 16 + lm) * H_ + kf * 32 + lk * 8];

    for (int i = tid; i < 16 * 136; i += 512) h_sh[i] = 0;
    const int hh = tid & 127, tq = tid >> 7;
    float c[4] = {0.f, 0.f, 0.f, 0.f};
    __syncthreads();

    for (int s = 0; s < 32; ++s) {
        const int b_idx = dir ? (31 - s) : s;
        const uint16_t* xp = Xp + ((size_t)(dir * B_ + b_idx) * T_ + t0) * G4_;
        uint16_t xv[4][4];
        #pragma unroll
        for (int j = 0; j < 4; ++j)
            #pragma unroll
            for (int gg = 0; gg < 4; ++gg)
                xv[j][gg] = xp[(size_t)(tq * 4 + j) * G4_ + gg * H_ + hh];

        short8 af[4];
        #pragma unroll
        for (int kf = 0; kf < 4; ++kf)
            af[kf] = *(const short8*)&h_sh[lm * 136 + kf * 32 + lk * 8];
        floatx4 acc[4] = {};
        #pragma unroll
        for (int nf = 0; nf < 4; ++nf)
            #pragma unroll
            for (int kf = 0; kf < 4; ++kf)
                acc[nf] = __builtin_amdgcn_mfma_f32_16x16x32_bf16(af[kf], bw[nf][kf], acc[nf], 0, 0, 0);
        #pragma unroll
        for (int nf = 0; nf < 4; ++nf)
            #pragma unroll
            for (int r = 0; r < 4; ++r)
                z_sh[(lk * 4 + r) * 516 + gw + nf * 16 + lm] = acc[nf][r];
        __syncthreads();

        #pragma unroll
        for (int j = 0; j < 4; ++j) {
            const int t = tq * 4 + j;
            const float* zr = &z_sh[t * 516];
            float zi = zr[hh]            + bf16_to_f(xv[j][0]);
            float zf = zr[H_ + hh]       + bf16_to_f(xv[j][1]);
            float zg = zr[2 * H_ + hh]   + bf16_to_f(xv[j][2]);
            float zo = zr[3 * H_ + hh]   + bf16_to_f(xv[j][3]);
            float si = rcpf(1.f + __builtin_amdgcn_exp2f(-LOG2E * zi));
            float sf = rcpf(1.f + __builtin_amdgcn_exp2f(-LOG2E * zf));
            float so = rcpf(1.f + __builtin_amdgcn_exp2f(-LOG2E * zo));
            float tg = 1.f - 2.f * rcpf(1.f + __builtin_amdgcn_exp2f(2.f * LOG2E * zg));
            c[j] = sf * c[j] + si * tg;
            float tc = 1.f - 2.f * rcpf(1.f + __builtin_amdgcn_exp2f(2.f * LOG2E * c[j]));
            float hn = so * tc;
            uint16_t hb = f_to_bf16(hn);
            h_sh[t * 136 + hh] = hb;
            hs[((size_t)b_idx * T_ + t0 + t) * 256 + dir * H_ + hh] = hb;
        }
        __syncthreads();
    }
}

// =====================================================================
// k_outm: out[b][e][t] fp32 = W_out(128x256) @ hs[b]^T + b_out
// 64x64 tiles, BK=64, grid (8, 2, 32)
// =====================================================================
__global__ __launch_bounds__(256) void k_outm(const uint16_t* __restrict__ WoutB,
                                              const uint16_t* __restrict__ hs,
                                              const float* __restrict__ bout,
                                              float* __restrict__ out) {
    __shared__ __align__(16) uint16_t As[4096], Bs[4096];
    const int b = blockIdx.z, m0 = blockIdx.y * 64, n0 = blockIdx.x * 64;
    const int tid = threadIdx.x, w = tid >> 6, l = tid & 63;
    const int wm = (w >> 1) * 32, wn = (w & 1) * 32;
    const int lm = l & 15, lk = l >> 4;
    const uint16_t* A = WoutB + (size_t)m0 * 256;
    const uint16_t* Bp = hs + ((size_t)b * T_ + n0) * 256;
    floatx4 acc[2][2] = {};
    const uint16_t* gA = A + (size_t)l * 256;
    const uint16_t* gB = Bp + (size_t)l * 256;
    for (int k0 = 0; k0 < 256; k0 += 64) {
        __syncthreads();
        gload16(gA + k0 + (2 * w) * 8,     As + ((2 * w) * 64 + l) * 8);
        gload16(gA + k0 + (2 * w + 1) * 8, As + ((2 * w + 1) * 64 + l) * 8);
        gload16(gB + k0 + (2 * w) * 8,     Bs + ((2 * w) * 64 + l) * 8);
        gload16(gB + k0 + (2 * w + 1) * 8, Bs + ((2 * w + 1) * 64 + l) * 8);
        __syncthreads();
        short8 a[2][2], bfr[2][2];
        #pragma unroll
        for (int kf = 0; kf < 2; ++kf) {
            #pragma unroll
            for (int mf = 0; mf < 2; ++mf)
                a[mf][kf] = *(const short8*)&As[((kf * 4 + lk) * 64 + wm + mf * 16 + lm) * 8];
            #pragma unroll
            for (int nf = 0; nf < 2; ++nf)
                bfr[nf][kf] = *(const short8*)&Bs[((kf * 4 + lk) * 64 + wn + nf * 16 + lm) * 8];
        }
        #pragma unroll
        for (int mf = 0; mf < 2; ++mf)
            #pragma unroll
            for (int nf = 0; nf < 2; ++nf) {
                acc[mf][nf] = __builtin_amdgcn_mfma_f32_16x16x32_bf16(a[mf][0], bfr[nf][0], acc[mf][nf], 0, 0, 0);
                acc[mf][nf] = __builtin_amdgcn_mfma_f32_16x16x32_bf16(a[mf][1], bfr[nf][1], acc[mf][nf], 0, 0, 0);
            }
    }
    #pragma unroll
    for (int mf = 0; mf < 2; ++mf) {
        const int e0 = m0 + wm + mf * 16 + lk * 4;
        const float4 bv = *(const float4*)&bout[e0];
        #pragma unroll
        for (int nf = 0; nf < 2; ++nf) {
            const int t = n0 + wn + nf * 16 + lm;
            out[((size_t)b * H_ + e0 + 0) * T_ + t] = acc[mf][nf][0] + bv.x;
            out[((size_t)b * H_ + e0 + 1) * T_ + t] = acc[mf][nf][1] + bv.y;
            out[((size_t)b * H_ + e0 + 2) * T_ + t] = acc[mf][nf][2] + bv.z;
            out[((size_t)b * H_ + e0 + 3) * T_ + t] = acc[mf][nf][3] + bv.w;
        }
    }
}

// =====================================================================
extern "C" void kernel_launch(void* const* d_in, const int* in_sizes, int n_in,
                              void* d_out, int out_size, void* d_ws, size_t ws_size,
                              hipStream_t stream) {
    const float* x     = (const float*)d_in[0];
    const float* Wfc   = (const float*)d_in[1];
    const float* bfc   = (const float*)d_in[2];
    const float* Wih_f = (const float*)d_in[3];
    const float* Whh_f = (const float*)d_in[4];
    const float* b_f   = (const float*)d_in[5];
    const float* Wih_b = (const float*)d_in[6];
    const float* Whh_b = (const float*)d_in[7];
    const float* b_b   = (const float*)d_in[8];
    const float* Wout  = (const float*)d_in[9];
    const float* bout  = (const float*)d_in[10];
    float* out = (float*)d_out;

    char* ws = (char*)d_ws;
    uint16_t* Xp    = (uint16_t*)(ws);                 // 33,554,432 B
    uint16_t* hsB   = (uint16_t*)(ws + 33554432);      //  8,388,608 B
    uint16_t* WfcB  = (uint16_t*)(ws + 41943040);      //    524,288 B
    uint16_t* WihB  = (uint16_t*)(ws + 42467328);      //    262,144 B
    uint16_t* WhhB  = (uint16_t*)(ws + 42729472);      //    262,144 B
    uint16_t* WoutB = (uint16_t*)(ws + 42991616);      //     65,536 B

    k_cvt_all<<<dim3(544), 256, 0, stream>>>(Wfc, Wih_f, Wih_b, Whh_f, Whh_b, Wout,
                                             WfcB, WihB, WhhB, WoutB);
    k_fc1x <<<dim3(8, 32),   512, 0, stream>>>(x, WfcB, bfc, WihB, b_f, b_b, Xp);
    k_lstm <<<dim3(32, 2),   512, 0, stream>>>(Xp, WhhB, hsB);
    k_outm <<<dim3(8, 2, 32), 256, 0, stream>>>(WoutB, hsB, bout, out);
}